// Round 17
// baseline (625.163 us; speedup 1.0000x reference)
//
#include <hip/hip_runtime.h>

// MLA v3 forward, MI355X/gfx950. Round 17.
// vs round 16: (1) attn loop order reverted to round-15 (proven 108.6us;
// round-16 "prefetch fix" was a 5us regression), exp2+defer-max kept.
// (2) rope_assemble ELIMINATED: rotation fused into GEMM epilogues via
// lane^1 shuffle (pairs are adjacent cols = adjacent lanes). G1(MODE 7)
// writes rope'd k_r to all heads' KCAT; G23(MODE 6) writes rope'd+scaled
// q_r directly to QCAT. QR buffer removed.

typedef unsigned short u16;
typedef __attribute__((ext_vector_type(8))) short s16x8;
typedef __attribute__((ext_vector_type(4))) float f32x4;
typedef __attribute__((ext_vector_type(8))) __bf16 bf16x8;
typedef __attribute__((ext_vector_type(4))) u16 u16x4;

#define S_LEN 2048
#define NH 16
#define HD 128
#define DQK 192
#define EMB 2048

#define GLOAD_LDS16(g, l)                                                      \
  __builtin_amdgcn_global_load_lds(                                            \
      (const __attribute__((address_space(1))) unsigned int*)(g),              \
      (__attribute__((address_space(3))) unsigned int*)(l), 16, 0, 0)

__device__ __forceinline__ u16 f2b(float f) {
  unsigned u = __builtin_bit_cast(unsigned, f);
  u += 0x7FFFu + ((u >> 16) & 1u);           // RNE to bf16
  return (u16)(u >> 16);
}
__device__ __forceinline__ float b2f(u16 v) {
  unsigned u = ((unsigned)v) << 16;
  return __builtin_bit_cast(float, u);
}
__device__ __forceinline__ bf16x8 ld_bf8(const u16* p) {
  return __builtin_bit_cast(bf16x8, *(const s16x8*)p);
}

// Transpose one 64x64 tile: in f32 [K][N] -> out bf16 [N][K].
__device__ __forceinline__ void transpose_tile(const float* __restrict__ in,
                                               u16* __restrict__ out,
                                               int K, int N, int local, int t,
                                               u16* T /* [64*72] LDS */) {
  int nt = N >> 6;
  int n0 = (local % nt) * 64, k0 = (local / nt) * 64;
#pragma unroll
  for (int r = 0; r < 4; ++r) {
    int kl = (t >> 4) + r * 16, nl = (t & 15) * 4;
    f32x4 v = *(const f32x4*)(in + (size_t)(k0 + kl) * N + n0 + nl);
#pragma unroll
    for (int j = 0; j < 4; ++j) T[(nl + j) * 72 + kl] = f2b(v[j]);
  }
  __syncthreads();
#pragma unroll
  for (int r = 0; r < 2; ++r) {
    int chunk = t + r * 256, nr = chunk >> 3, kc = (chunk & 7) * 8;
    *(s16x8*)(out + (size_t)(n0 + nr) * K + k0 + kc) = *(const s16x8*)(&T[nr * 72 + kc]);
  }
}

// Fused prep: [0,8192) f2b(x); then 8 weight transposes; then rope table.
__global__ __launch_bounds__(256) void prep_kernel(
    const float* __restrict__ xf, u16* __restrict__ XB,
    const float* __restrict__ wckvf, u16* __restrict__ WCKV_T,
    const float* __restrict__ wcqf,  u16* __restrict__ WCQ_T,
    const float* __restrict__ wkrf,  u16* __restrict__ WKR_T,
    const float* __restrict__ wkf,   u16* __restrict__ WK_T,
    const float* __restrict__ wvf,   u16* __restrict__ WV_T,
    const float* __restrict__ wqf,   u16* __restrict__ WQ_T,
    const float* __restrict__ wqrf,  u16* __restrict__ WQR_T,
    const float* __restrict__ wof,   u16* __restrict__ WO_T,
    float* __restrict__ cosT, float* __restrict__ sinT) {
  __shared__ u16 T[64 * 72];
  const int id = blockIdx.x, t = threadIdx.x;
  if (id < 8192) {                       // x f32 -> bf16, 4 el/thread
    int i = id * 256 + t;                // n4 = 2097152 exactly
    f32x4 v = *(const f32x4*)(xf + (size_t)i * 4);
    u16x4 o = { f2b(v[0]), f2b(v[1]), f2b(v[2]), f2b(v[3]) };
    *(u16x4*)(XB + (size_t)i * 4) = o;
  } else if (id < 8448)  { transpose_tile(wckvf, WCKV_T, 2048, 512,  id - 8192, t, T); }
  else if (id < 8704)    { transpose_tile(wcqf,  WCQ_T,  2048, 512,  id - 8448, t, T); }
  else if (id < 8736)    { transpose_tile(wkrf,  WKR_T,  2048, 64,   id - 8704, t, T); }
  else if (id < 8992)    { transpose_tile(wkf,   WK_T,   512,  2048, id - 8736, t, T); }
  else if (id < 9248)    { transpose_tile(wvf,   WV_T,   512,  2048, id - 8992, t, T); }
  else if (id < 9504)    { transpose_tile(wqf,   WQ_T,   512,  2048, id - 9248, t, T); }
  else if (id < 9632)    { transpose_tile(wqrf,  WQR_T,  512,  1024, id - 9504, t, T); }
  else if (id < 10656)   { transpose_tile(wof,   WO_T,   2048, 2048, id - 9632, t, T); }
  else {                                 // rope cos/sin table, 65536 entries
    int i2 = (id - 10656) * 256 + t;
    int s = i2 >> 5, i = i2 & 31;
    float inv = exp2f(-(float)i * (13.287712379549449f / 32.0f));
    float ang = (float)s * inv;
    cosT[i2] = cosf(ang);
    sinT[i2] = sinf(ang);
  }
}

// C = A[M,K](lda) @ BT[N,K]^T, bf16 in, fp32 accum. 128x128 tile, BK=64.
// 1D grid + XCD-chunked swizzle (gridDim.x % 8 == 0 required).
// MODE 1: fp32 [M,N]->C0.
// MODE 7 (G1, N=1088): col<1024 -> CC(C0)[M,1088]; col>=1024 -> rope(k_r)
//   broadcast to all 16 heads of KCAT(C1)[...,128+d].
// MODE 6 (G23, N=7168, bn0>=4096 uses A+512):
//   col<2048 -> KCAT(C0)[b,h,s,192] d<128; col<4096 -> VT(C1)[b,h,d,s];
//   col<6144 -> QCAT(C2)*scale; else -> rope(q_r)*scale -> QCAT(C2)[...,128+d].
template<int MODE>
__global__ __launch_bounds__(256) void gemm_bt_kernel(const u16* __restrict__ A,
                                                      int lda,
                                                      const u16* __restrict__ BT,
                                                      void* __restrict__ C0,
                                                      void* __restrict__ C1,
                                                      void* __restrict__ C2,
                                                      const float* __restrict__ cosT,
                                                      const float* __restrict__ sinT,
                                                      int M, int N, int K,
                                                      int nx, float scale) {
  __shared__ __align__(16) u16 As[2][128 * 64];
  __shared__ __align__(16) u16 Bs[2][128 * 64];
  const int t = threadIdx.x;
  const int lane = t & 63, wid = t >> 6;
  const int wr = (wid >> 1) * 64, wc = (wid & 1) * 64;
  const int cpx = gridDim.x >> 3;
  int wg = blockIdx.x;
  wg = (wg & 7) * cpx + (wg >> 3);
  const int bn0 = (wg % nx) * 128;
  const int bm0 = (wg / nx) * 128;
  if (MODE == 6 && bn0 >= 4096) A += 512;   // G3 part reads c_q slice
  const int lr = lane & 15, lg = lane >> 4;

  auto stage = [&](int k0, int buf) {
#pragma unroll
    for (int r = 0; r < 4; ++r) {
      int chunk = t + r * 256;
      int row = chunk >> 3, kcs = (chunk & 7) * 8;
      int kcg = kcs ^ ((row & 7) << 3);      // inverse swizzle on SOURCE
      GLOAD_LDS16(A + (size_t)(bm0 + row) * lda + k0 + kcg, &As[buf][chunk * 8]);
      GLOAD_LDS16(BT + (size_t)(bn0 + row) * K + k0 + kcg, &Bs[buf][chunk * 8]);
    }
  };

  f32x4 acc[4][4] = {};
  const int nt = K >> 6;
  stage(0, 0);
  for (int tk = 0; tk < nt; ++tk) {
    const int cur = tk & 1;
    __syncthreads();
    if (tk + 1 < nt) stage((tk + 1) << 6, cur ^ 1);
#pragma unroll
    for (int kk = 0; kk < 2; ++kk) {
      bf16x8 af[4], bfr[4];
      const int kbase = kk * 32 + lg * 8;
#pragma unroll
      for (int m = 0; m < 4; ++m) {
        int row = wr + m * 16 + lr;
        af[m] = ld_bf8(&As[cur][row * 64 + (kbase ^ ((row & 7) << 3))]);
      }
#pragma unroll
      for (int n = 0; n < 4; ++n) {
        int row = wc + n * 16 + lr;
        bfr[n] = ld_bf8(&Bs[cur][row * 64 + (kbase ^ ((row & 7) << 3))]);
      }
#pragma unroll
      for (int m = 0; m < 4; ++m)
#pragma unroll
        for (int n = 0; n < 4; ++n)
          acc[m][n] = __builtin_amdgcn_mfma_f32_16x16x32_bf16(af[m], bfr[n], acc[m][n], 0, 0, 0);
    }
  }

  // C/D layout: col = lane&15, row = (lane>>4)*4 + reg
#pragma unroll
  for (int m = 0; m < 4; ++m)
#pragma unroll
    for (int n = 0; n < 4; ++n)
#pragma unroll
      for (int rg = 0; rg < 4; ++rg) {
        int row = bm0 + wr + m * 16 + lg * 4 + rg;
        int col = bn0 + wc + n * 16 + lr;
        float v = acc[m][n][rg];
        // rope partner (lane^1) BEFORE any lane-divergent continue
        float p = (MODE == 6 || MODE == 7) ? __shfl_xor(v, 1, 64) : 0.f;
        if (col >= N) continue;
        if (MODE == 1) {
          ((float*)C0)[(size_t)row * N + col] = v * scale;
        } else if (MODE == 7) {
          if (col < 1024) {
            ((u16*)C0)[(size_t)row * 1088 + col] = f2b(v);
          } else {
            int s = row & 2047, bb = row >> 11, d = col & 63, i = d >> 1;
            float c = cosT[(s << 5) + i], sn = sinT[(s << 5) + i];
            float out = ((lr & 1) == 0) ? (v * c - p * sn) : (p * sn + v * c);
            u16 o = f2b(out);
#pragma unroll
            for (int hh = 0; hh < 16; ++hh)
              ((u16*)C1)[((size_t)(bb * NH + hh) * S_LEN + s) * DQK + HD + d] = o;
          }
        } else {  // MODE 6
          int bb = row >> 11, s = row & 2047;
          if (col < 2048) {
            int h = col >> 7, d = col & 127;
            ((u16*)C0)[((size_t)(bb * NH + h) * S_LEN + s) * DQK + d] = f2b(v);
          } else if (col < 4096) {
            int c2 = col - 2048, h = c2 >> 7, d = c2 & 127;
            ((u16*)C1)[((size_t)(bb * NH + h) * HD + d) * S_LEN + s] = f2b(v);
          } else if (col < 6144) {
            int c3 = col - 4096, h = c3 >> 7, d = c3 & 127;
            ((u16*)C2)[((size_t)(bb * NH + h) * S_LEN + s) * DQK + d] = f2b(v * scale);
          } else {
            int dd = col - 6144, h = dd >> 6, d = dd & 63, i = d >> 1;
            float c = cosT[(s << 5) + i], sn = sinT[(s << 5) + i];
            float out = (((lr & 1) == 0) ? (v * c - p * sn) : (p * sn + v * c)) * scale;
            ((u16*)C2)[((size_t)(bb * NH + h) * S_LEN + s) * DQK + HD + d] = f2b(out);
          }
        }
      }
}

// Flash attention, causal. Round-15 structure (proven) + exp2 softmax +
// defer-max. 8 waves, QBLK=128, kv tile 64. Grid 512; balanced decode.
__global__ __launch_bounds__(512, 2) void attn_kernel(const u16* __restrict__ Q,
                                                      const u16* __restrict__ K,
                                                      const u16* __restrict__ VT,
                                                      u16* __restrict__ O) {
  __shared__ u16 Ks[64 * 200];    // [kv][d0..191]
  __shared__ u16 Vs[128 * 72];    // [d][kv0..63]
  __shared__ u16 Ps[8 * 16 * 88]; // per-wave [q][kv]
  const int id = blockIdx.x;
  const int p8 = id >> 5, hb = id & 31;
  const int h = hb & 15, b = hb >> 4;
  const int qb = (p8 < 8) ? p8 : 23 - p8;
  const int q0 = qb * 128;
  const int t = threadIdx.x, lane = t & 63, wid = t >> 6;
  const int lr = lane & 15, lg = lane >> 4;
  const size_t qk_head = (size_t)(b * NH + h) * S_LEN * DQK;
  const size_t vt_head = (size_t)(b * NH + h) * HD * S_LEN;

  s16x8 kst[3], vst[2];
  auto gload = [&](int kt) {
#pragma unroll
    for (int r = 0; r < 3; ++r) {
      int chunk = t + r * 512, row = chunk / 24, cc = chunk % 24;
      kst[r] = *(const s16x8*)(K + qk_head + (size_t)(kt * 64 + row) * DQK + cc * 8);
    }
#pragma unroll
    for (int r = 0; r < 2; ++r) {
      int chunk = t + r * 512, d = chunk >> 3, cc = chunk & 7;
      vst[r] = *(const s16x8*)(VT + vt_head + (size_t)d * S_LEN + kt * 64 + cc * 8);
    }
  };
  auto swr = [&]() {
#pragma unroll
    for (int r = 0; r < 3; ++r) {
      int chunk = t + r * 512, row = chunk / 24, cc = chunk % 24;
      *(s16x8*)(&Ks[row * 200 + cc * 8]) = kst[r];
    }
#pragma unroll
    for (int r = 0; r < 2; ++r) {
      int chunk = t + r * 512, d = chunk >> 3, cc = chunk & 7;
      *(s16x8*)(&Vs[d * 72 + cc * 8]) = vst[r];
    }
  };

  bf16x8 qa[6];
  {
    const u16* qrow = Q + qk_head + (size_t)(q0 + wid * 16 + lr) * DQK;
#pragma unroll
    for (int ks = 0; ks < 6; ++ks) qa[ks] = ld_bf8(qrow + ks * 32 + lg * 8);
  }

  f32x4 acc_o[8] = {};
  float m_r[4] = { -INFINITY, -INFINITY, -INFINITY, -INFINITY };
  float l_r[4] = { 0.f, 0.f, 0.f, 0.f };

  const int nt = 2 * qb + 2;
  gload(0);
#pragma unroll 1
  for (int kt = 0; kt < nt; ++kt) {
    __syncthreads();                 // all waves done reading previous tile
    swr();                           // stage tile kt
    if (kt + 1 < nt) gload(kt + 1);  // prefetch next
    __syncthreads();                 // tile kt visible

    f32x4 sacc[4];
#pragma unroll
    for (int cb = 0; cb < 4; ++cb) {
      f32x4 sv = {};
#pragma unroll
      for (int ks = 0; ks < 6; ++ks) {
        bf16x8 kb = ld_bf8(&Ks[(cb * 16 + lr) * 200 + ks * 32 + lg * 8]);
        sv = __builtin_amdgcn_mfma_f32_16x16x32_bf16(qa[ks], kb, sv, 0, 0, 0);
      }
      sacc[cb] = sv;
    }

    if (kt >= 2 * qb) {              // diagonal tiles: causal mask
#pragma unroll
      for (int cb = 0; cb < 4; ++cb)
#pragma unroll
        for (int rg = 0; rg < 4; ++rg) {
          int q_g = q0 + wid * 16 + lg * 4 + rg;
          int kv_g = kt * 64 + cb * 16 + lr;
          if (kv_g > q_g) sacc[cb][rg] = -INFINITY;
        }
    }

    float pmax[4];
#pragma unroll
    for (int rg = 0; rg < 4; ++rg)
      pmax[rg] = fmaxf(fmaxf(sacc[0][rg], sacc[1][rg]), fmaxf(sacc[2][rg], sacc[3][rg]));
#pragma unroll
    for (int off = 1; off < 16; off <<= 1)
#pragma unroll
      for (int rg = 0; rg < 4; ++rg)
        pmax[rg] = fmaxf(pmax[rg], __shfl_xor(pmax[rg], off, 64));

    // defer-max: skip O-rescale when per-tile max growth <= 8 (log2 domain).
    int nochange = (pmax[0] <= m_r[0] + 8.f) & (pmax[1] <= m_r[1] + 8.f) &
                   (pmax[2] <= m_r[2] + 8.f) & (pmax[3] <= m_r[3] + 8.f);
    if (!__all(nochange)) {
      float alpha[4];
#pragma unroll
      for (int rg = 0; rg < 4; ++rg) {
        float mn = fmaxf(m_r[rg], pmax[rg]);
        alpha[rg] = exp2f(m_r[rg] - mn);
        m_r[rg] = mn;
        l_r[rg] *= alpha[rg];
      }
#pragma unroll
      for (int vb = 0; vb < 8; ++vb)
#pragma unroll
        for (int rg = 0; rg < 4; ++rg)
          acc_o[vb][rg] *= alpha[rg];
    }

    float psum[4] = { 0.f, 0.f, 0.f, 0.f };
#pragma unroll
    for (int cb = 0; cb < 4; ++cb)
#pragma unroll
      for (int rg = 0; rg < 4; ++rg) {
        float pv = exp2f(sacc[cb][rg] - m_r[rg]);
        sacc[cb][rg] = pv;
        psum[rg] += pv;
      }
#pragma unroll
    for (int off = 1; off < 16; off <<= 1)
#pragma unroll
      for (int rg = 0; rg < 4; ++rg)
        psum[rg] += __shfl_xor(psum[rg], off, 64);
#pragma unroll
    for (int rg = 0; rg < 4; ++rg) l_r[rg] += psum[rg];

    // P -> per-wave LDS (same-wave RAW only)
    u16* psw = &Ps[wid * (16 * 88)];
#pragma unroll
    for (int cb = 0; cb < 4; ++cb)
#pragma unroll
      for (int rg = 0; rg < 4; ++rg)
        psw[(lg * 4 + rg) * 88 + cb * 16 + lr] = f2b(sacc[cb][rg]);

    bf16x8 pa[2];
#pragma unroll
    for (int ks = 0; ks < 2; ++ks) pa[ks] = ld_bf8(&psw[lr * 88 + ks * 32 + lg * 8]);
#pragma unroll
    for (int vb = 0; vb < 8; ++vb) {
#pragma unroll
      for (int ks = 0; ks < 2; ++ks) {
        bf16x8 vv = ld_bf8(&Vs[(vb * 16 + lr) * 72 + ks * 32 + lg * 8]);
        acc_o[vb] = __builtin_amdgcn_mfma_f32_16x16x32_bf16(pa[ks], vv, acc_o[vb], 0, 0, 0);
      }
    }
  }

  // epilogue: O[b][s][h*128+d] bf16
#pragma unroll
  for (int vb = 0; vb < 8; ++vb)
#pragma unroll
    for (int rg = 0; rg < 4; ++rg) {
      int s_glob = q0 + wid * 16 + lg * 4 + rg;
      int col = vb * 16 + lr;
      O[((size_t)b * S_LEN + s_glob) * EMB + h * HD + col] = f2b(acc_o[vb][rg] / l_r[rg]);
    }
}

extern "C" void kernel_launch(void* const* d_in, const int* in_sizes, int n_in,
                              void* d_out, int out_size, void* d_ws, size_t ws_size,
                              hipStream_t stream) {
  const float* xf    = (const float*)d_in[0];
  const float* wckvf = (const float*)d_in[1];
  const float* wkf   = (const float*)d_in[2];
  const float* wvf   = (const float*)d_in[3];
  const float* wcqf  = (const float*)d_in[4];
  const float* wqf   = (const float*)d_in[5];
  const float* wqrf  = (const float*)d_in[6];
  const float* wkrf  = (const float*)d_in[7];
  const float* wof   = (const float*)d_in[8];
  (void)in_sizes; (void)n_in; (void)out_size; (void)ws_size;

  u16* ws = (u16*)d_ws;
  size_t off = 0;
  auto alloc = [&](size_t n) -> u16* { u16* p = ws + off; off += n; return p; };
  u16* XB     = alloc(8388608);   // x bf16 [4096,2048]
  // W1_T group [1088,2048]: wckv rows 0..511, wcq 512..1023, wkr 1024..1087
  u16* WCKV_T = alloc(1048576);
  u16* WCQ_T  = alloc(1048576);
  u16* WKR_T  = alloc(131072);
  // Fused weight block [7168,512]: wk | wv | wq | wqr
  u16* WK_T   = alloc(1048576);
  u16* WV_T   = alloc(1048576);
  u16* WQ_T   = alloc(1048576);
  u16* WQR_T  = alloc(524288);
  u16* WO_T   = alloc(4194304);   // [2048,2048]
  u16* CC     = alloc(4456448);   // [4096,1088]: ckv | cq | (kr unused)
  u16* QCAT   = alloc(12582912);  // [B,H,S,192]
  u16* KCAT   = alloc(12582912);
  u16* VT     = alloc(8388608);   // [B,H,128,S]
  u16* AOUT   = alloc(8388608);   // [4096,2048]
  float* COS_T = (float*)alloc(131072);
  float* SIN_T = (float*)alloc(131072);

  // Fused prep: f2b(x) + all weight transposes + rope table.
  prep_kernel<<<10912, 256, 0, stream>>>(xf, XB,
                                         wckvf, WCKV_T, wcqf, WCQ_T, wkrf, WKR_T,
                                         wkf, WK_T, wvf, WV_T, wqf, WQ_T,
                                         wqrf, WQR_T, wof, WO_T,
                                         COS_T, SIN_T);

  const float SC = 0.07216878364870323f * 1.4426950408889634f;  // 1/sqrt(192)*log2e
  // G1: x @ [w_ckv | w_cq | w_kr] -> CC + rope(k_r)->KCAT. 288 blocks.
  gemm_bt_kernel<7><<<288, 256, 0, stream>>>(XB, 2048, WCKV_T, CC, KCAT, nullptr,
                                             COS_T, SIN_T,
                                             4096, 1088, 2048, 9, 1.0f);
  // G23: {c_kv,c_q} @ [wk|wv|wq|wqr] -> KCAT + VT + QCAT (incl. rope'd q_r).
  gemm_bt_kernel<6><<<1792, 256, 0, stream>>>(CC, 1088, WK_T, KCAT, VT, QCAT,
                                              COS_T, SIN_T,
                                              4096, 7168, 512, 56, SC);

  attn_kernel<<<512, 512, 0, stream>>>(QCAT, KCAT, VT, AOUT);

  // G4: attn_out @ w_o -> d_out (fp32). 512 blocks.
  gemm_bt_kernel<1><<<512, 256, 0, stream>>>(AOUT, 2048, WO_T, d_out,
                                             nullptr, nullptr,
                                             nullptr, nullptr,
                                             4096, 2048, 2048, 16, 1.0f);
}

// Round 18
// 276.455 us; speedup vs baseline: 2.2614x; 2.2614x over previous
//
#include <hip/hip_runtime.h>

// MLA v3 forward, MI355X/gfx950. Round 18 = revert to round-15 champion
// (270.95us) + exp2 softmax. Round-17's rope-in-GEMM fusion regressed 2.3x
// (16-way scalar broadcast in MODE 7 -> 456MB write amplification on 32
// straggler blocks); separate rope_assemble kernel restored.

typedef unsigned short u16;
typedef __attribute__((ext_vector_type(8))) short s16x8;
typedef __attribute__((ext_vector_type(4))) float f32x4;
typedef __attribute__((ext_vector_type(8))) __bf16 bf16x8;
typedef __attribute__((ext_vector_type(4))) u16 u16x4;

#define S_LEN 2048
#define NH 16
#define HD 128
#define DQK 192
#define EMB 2048

#define GLOAD_LDS16(g, l)                                                      \
  __builtin_amdgcn_global_load_lds(                                            \
      (const __attribute__((address_space(1))) unsigned int*)(g),              \
      (__attribute__((address_space(3))) unsigned int*)(l), 16, 0, 0)

__device__ __forceinline__ u16 f2b(float f) {
  unsigned u = __builtin_bit_cast(unsigned, f);
  u += 0x7FFFu + ((u >> 16) & 1u);           // RNE to bf16
  return (u16)(u >> 16);
}
__device__ __forceinline__ float b2f(u16 v) {
  unsigned u = ((unsigned)v) << 16;
  return __builtin_bit_cast(float, u);
}
__device__ __forceinline__ bf16x8 ld_bf8(const u16* p) {
  return __builtin_bit_cast(bf16x8, *(const s16x8*)p);
}

// Transpose one 64x64 tile: in f32 [K][N] -> out bf16 [N][K].
__device__ __forceinline__ void transpose_tile(const float* __restrict__ in,
                                               u16* __restrict__ out,
                                               int K, int N, int local, int t,
                                               u16* T /* [64*72] LDS */) {
  int nt = N >> 6;
  int n0 = (local % nt) * 64, k0 = (local / nt) * 64;
#pragma unroll
  for (int r = 0; r < 4; ++r) {
    int kl = (t >> 4) + r * 16, nl = (t & 15) * 4;
    f32x4 v = *(const f32x4*)(in + (size_t)(k0 + kl) * N + n0 + nl);
#pragma unroll
    for (int j = 0; j < 4; ++j) T[(nl + j) * 72 + kl] = f2b(v[j]);
  }
  __syncthreads();
#pragma unroll
  for (int r = 0; r < 2; ++r) {
    int chunk = t + r * 256, nr = chunk >> 3, kc = (chunk & 7) * 8;
    *(s16x8*)(out + (size_t)(n0 + nr) * K + k0 + kc) = *(const s16x8*)(&T[nr * 72 + kc]);
  }
}

// Fused prep: [0,8192) f2b(x); then 8 weight transposes; then rope table.
__global__ __launch_bounds__(256) void prep_kernel(
    const float* __restrict__ xf, u16* __restrict__ XB,
    const float* __restrict__ wckvf, u16* __restrict__ WCKV_T,
    const float* __restrict__ wcqf,  u16* __restrict__ WCQ_T,
    const float* __restrict__ wkrf,  u16* __restrict__ WKR_T,
    const float* __restrict__ wkf,   u16* __restrict__ WK_T,
    const float* __restrict__ wvf,   u16* __restrict__ WV_T,
    const float* __restrict__ wqf,   u16* __restrict__ WQ_T,
    const float* __restrict__ wqrf,  u16* __restrict__ WQR_T,
    const float* __restrict__ wof,   u16* __restrict__ WO_T,
    float* __restrict__ cosT, float* __restrict__ sinT) {
  __shared__ u16 T[64 * 72];
  const int id = blockIdx.x, t = threadIdx.x;
  if (id < 8192) {                       // x f32 -> bf16, 4 el/thread
    int i = id * 256 + t;                // n4 = 2097152 exactly
    f32x4 v = *(const f32x4*)(xf + (size_t)i * 4);
    u16x4 o = { f2b(v[0]), f2b(v[1]), f2b(v[2]), f2b(v[3]) };
    *(u16x4*)(XB + (size_t)i * 4) = o;
  } else if (id < 8448)  { transpose_tile(wckvf, WCKV_T, 2048, 512,  id - 8192, t, T); }
  else if (id < 8704)    { transpose_tile(wcqf,  WCQ_T,  2048, 512,  id - 8448, t, T); }
  else if (id < 8736)    { transpose_tile(wkrf,  WKR_T,  2048, 64,   id - 8704, t, T); }
  else if (id < 8992)    { transpose_tile(wkf,   WK_T,   512,  2048, id - 8736, t, T); }
  else if (id < 9248)    { transpose_tile(wvf,   WV_T,   512,  2048, id - 8992, t, T); }
  else if (id < 9504)    { transpose_tile(wqf,   WQ_T,   512,  2048, id - 9248, t, T); }
  else if (id < 9632)    { transpose_tile(wqrf,  WQR_T,  512,  1024, id - 9504, t, T); }
  else if (id < 10656)   { transpose_tile(wof,   WO_T,   2048, 2048, id - 9632, t, T); }
  else {                                 // rope cos/sin table, 65536 entries
    int i2 = (id - 10656) * 256 + t;
    int s = i2 >> 5, i = i2 & 31;
    float inv = exp2f(-(float)i * (13.287712379549449f / 32.0f));
    float ang = (float)s * inv;
    cosT[i2] = cosf(ang);
    sinT[i2] = sinf(ang);
  }
}

// C = A[M,K](lda) @ BT[N,K]^T, bf16 in, fp32 accum. 128x128 tile, BK=64.
// 1D grid + XCD-chunked swizzle (gridDim.x % 8 == 0 required).
// MODE 0: bf16 [M,N]->C0; MODE 1: fp32 [M,N]->C0;
// MODE 6 (fused G2+G3, N=7168, bn0>=4096 uses A+512):
//   col<2048 -> KCAT(C0)[b,h,s,192]; col<4096 -> VT(C1)[b,h,d,s];
//   col<6144 -> QCAT(C2)*scale; else -> QR(C3)[M,1024].
template<int MODE>
__global__ __launch_bounds__(256) void gemm_bt_kernel(const u16* __restrict__ A,
                                                      int lda,
                                                      const u16* __restrict__ BT,
                                                      void* __restrict__ C0,
                                                      void* __restrict__ C1,
                                                      void* __restrict__ C2,
                                                      void* __restrict__ C3,
                                                      int M, int N, int K,
                                                      int nx, float scale) {
  __shared__ __align__(16) u16 As[2][128 * 64];
  __shared__ __align__(16) u16 Bs[2][128 * 64];
  const int t = threadIdx.x;
  const int lane = t & 63, wid = t >> 6;
  const int wr = (wid >> 1) * 64, wc = (wid & 1) * 64;
  const int cpx = gridDim.x >> 3;
  int wg = blockIdx.x;
  wg = (wg & 7) * cpx + (wg >> 3);
  const int bn0 = (wg % nx) * 128;
  const int bm0 = (wg / nx) * 128;
  if (MODE == 6 && bn0 >= 4096) A += 512;   // G3 part reads c_q slice
  const int lr = lane & 15, lg = lane >> 4;

  auto stage = [&](int k0, int buf) {
#pragma unroll
    for (int r = 0; r < 4; ++r) {
      int chunk = t + r * 256;
      int row = chunk >> 3, kcs = (chunk & 7) * 8;
      int kcg = kcs ^ ((row & 7) << 3);      // inverse swizzle on SOURCE
      GLOAD_LDS16(A + (size_t)(bm0 + row) * lda + k0 + kcg, &As[buf][chunk * 8]);
      GLOAD_LDS16(BT + (size_t)(bn0 + row) * K + k0 + kcg, &Bs[buf][chunk * 8]);
    }
  };

  f32x4 acc[4][4] = {};
  const int nt = K >> 6;
  stage(0, 0);
  for (int tk = 0; tk < nt; ++tk) {
    const int cur = tk & 1;
    __syncthreads();
    if (tk + 1 < nt) stage((tk + 1) << 6, cur ^ 1);
#pragma unroll
    for (int kk = 0; kk < 2; ++kk) {
      bf16x8 af[4], bfr[4];
      const int kbase = kk * 32 + lg * 8;
#pragma unroll
      for (int m = 0; m < 4; ++m) {
        int row = wr + m * 16 + lr;
        af[m] = ld_bf8(&As[cur][row * 64 + (kbase ^ ((row & 7) << 3))]);
      }
#pragma unroll
      for (int n = 0; n < 4; ++n) {
        int row = wc + n * 16 + lr;
        bfr[n] = ld_bf8(&Bs[cur][row * 64 + (kbase ^ ((row & 7) << 3))]);
      }
#pragma unroll
      for (int m = 0; m < 4; ++m)
#pragma unroll
        for (int n = 0; n < 4; ++n)
          acc[m][n] = __builtin_amdgcn_mfma_f32_16x16x32_bf16(af[m], bfr[n], acc[m][n], 0, 0, 0);
    }
  }

  // C/D layout: col = lane&15, row = (lane>>4)*4 + reg
#pragma unroll
  for (int m = 0; m < 4; ++m)
#pragma unroll
    for (int n = 0; n < 4; ++n)
#pragma unroll
      for (int rg = 0; rg < 4; ++rg) {
        int row = bm0 + wr + m * 16 + lg * 4 + rg;
        int col = bn0 + wc + n * 16 + lr;
        if (col >= N) continue;
        float v = acc[m][n][rg];
        if (MODE == 0) {
          ((u16*)C0)[(size_t)row * N + col] = f2b(v * scale);
        } else if (MODE == 1) {
          ((float*)C0)[(size_t)row * N + col] = v * scale;
        } else {  // MODE 6
          int bb = row >> 11, s = row & 2047;
          if (col < 2048) {
            int h = col >> 7, d = col & 127;
            ((u16*)C0)[((size_t)(bb * NH + h) * S_LEN + s) * DQK + d] = f2b(v);
          } else if (col < 4096) {
            int c2 = col - 2048, h = c2 >> 7, d = c2 & 127;
            ((u16*)C1)[((size_t)(bb * NH + h) * HD + d) * S_LEN + s] = f2b(v);
          } else if (col < 6144) {
            int c3 = col - 4096, h = c3 >> 7, d = c3 & 127;
            ((u16*)C2)[((size_t)(bb * NH + h) * S_LEN + s) * DQK + d] = f2b(v * scale);
          } else {
            ((u16*)C3)[(size_t)row * 1024 + (col - 6144)] = f2b(v);
          }
        }
      }
}

// Fill rope halves of Qcat/Kcat. kr lives in CC cols 1024..1087 (stride 1088).
// Q rope half scaled by SC*log2(e) (exp2 softmax domain).
__global__ __launch_bounds__(256) void rope_assemble_kernel(const u16* __restrict__ qr,
                                                            const u16* __restrict__ cc,
                                                            const float* __restrict__ cosT,
                                                            const float* __restrict__ sinT,
                                                            u16* __restrict__ Qcat,
                                                            u16* __restrict__ Kcat) {
  int id = blockIdx.x * 256 + threadIdx.x;   // B*H*S*32 = 2^21
  int i = id & 31;
  int s = (id >> 5) & 2047;
  int h = (id >> 16) & 15;
  int b = id >> 20;
  float c = cosT[(s << 5) + i], sn = sinT[(s << 5) + i];
  const float SC = 0.07216878364870323f * 1.4426950408889634f;  // 1/sqrt(192)*log2e

  size_t qbase = ((size_t)b * S_LEN + s) * 1024 + h * 64 + 2 * i;
  float qe = b2f(qr[qbase]), qo = b2f(qr[qbase + 1]);
  size_t obase = ((size_t)(b * NH + h) * S_LEN + s) * DQK + HD + 2 * i;
  Qcat[obase]     = f2b((qe * c - qo * sn) * SC);
  Qcat[obase + 1] = f2b((qe * sn + qo * c) * SC);

  size_t kbase = ((size_t)b * S_LEN + s) * 1088 + 1024 + 2 * i;
  float ke = b2f(cc[kbase]), ko = b2f(cc[kbase + 1]);
  Kcat[obase]     = f2b(ke * c - ko * sn);
  Kcat[obase + 1] = f2b(ke * sn + ko * c);
}

// Flash attention, causal. Round-15 structure + exp2 softmax + defer-max.
// 8 waves, QBLK=128, kv tile 64. Grid 512; balanced decode.
__global__ __launch_bounds__(512, 2) void attn_kernel(const u16* __restrict__ Q,
                                                      const u16* __restrict__ K,
                                                      const u16* __restrict__ VT,
                                                      u16* __restrict__ O) {
  __shared__ u16 Ks[64 * 200];    // [kv][d0..191]
  __shared__ u16 Vs[128 * 72];    // [d][kv0..63]
  __shared__ u16 Ps[8 * 16 * 88]; // per-wave [q][kv]
  const int id = blockIdx.x;
  const int p8 = id >> 5, hb = id & 31;
  const int h = hb & 15, b = hb >> 4;
  const int qb = (p8 < 8) ? p8 : 23 - p8;
  const int q0 = qb * 128;
  const int t = threadIdx.x, lane = t & 63, wid = t >> 6;
  const int lr = lane & 15, lg = lane >> 4;
  const size_t qk_head = (size_t)(b * NH + h) * S_LEN * DQK;
  const size_t vt_head = (size_t)(b * NH + h) * HD * S_LEN;

  s16x8 kst[3], vst[2];
  auto gload = [&](int kt) {
#pragma unroll
    for (int r = 0; r < 3; ++r) {
      int chunk = t + r * 512, row = chunk / 24, cc = chunk % 24;
      kst[r] = *(const s16x8*)(K + qk_head + (size_t)(kt * 64 + row) * DQK + cc * 8);
    }
#pragma unroll
    for (int r = 0; r < 2; ++r) {
      int chunk = t + r * 512, d = chunk >> 3, cc = chunk & 7;
      vst[r] = *(const s16x8*)(VT + vt_head + (size_t)d * S_LEN + kt * 64 + cc * 8);
    }
  };
  auto swr = [&]() {
#pragma unroll
    for (int r = 0; r < 3; ++r) {
      int chunk = t + r * 512, row = chunk / 24, cc = chunk % 24;
      *(s16x8*)(&Ks[row * 200 + cc * 8]) = kst[r];
    }
#pragma unroll
    for (int r = 0; r < 2; ++r) {
      int chunk = t + r * 512, d = chunk >> 3, cc = chunk & 7;
      *(s16x8*)(&Vs[d * 72 + cc * 8]) = vst[r];
    }
  };

  bf16x8 qa[6];
  {
    const u16* qrow = Q + qk_head + (size_t)(q0 + wid * 16 + lr) * DQK;
#pragma unroll
    for (int ks = 0; ks < 6; ++ks) qa[ks] = ld_bf8(qrow + ks * 32 + lg * 8);
  }

  f32x4 acc_o[8] = {};
  float m_r[4] = { -INFINITY, -INFINITY, -INFINITY, -INFINITY };
  float l_r[4] = { 0.f, 0.f, 0.f, 0.f };

  const int nt = 2 * qb + 2;
  gload(0);
#pragma unroll 1
  for (int kt = 0; kt < nt; ++kt) {
    __syncthreads();                 // all waves done reading previous tile
    swr();                           // stage tile kt
    if (kt + 1 < nt) gload(kt + 1);  // prefetch next
    __syncthreads();                 // tile kt visible

    f32x4 sacc[4];
#pragma unroll
    for (int cb = 0; cb < 4; ++cb) {
      f32x4 sv = {};
#pragma unroll
      for (int ks = 0; ks < 6; ++ks) {
        bf16x8 kb = ld_bf8(&Ks[(cb * 16 + lr) * 200 + ks * 32 + lg * 8]);
        sv = __builtin_amdgcn_mfma_f32_16x16x32_bf16(qa[ks], kb, sv, 0, 0, 0);
      }
      sacc[cb] = sv;
    }

    if (kt >= 2 * qb) {              // diagonal tiles: causal mask
#pragma unroll
      for (int cb = 0; cb < 4; ++cb)
#pragma unroll
        for (int rg = 0; rg < 4; ++rg) {
          int q_g = q0 + wid * 16 + lg * 4 + rg;
          int kv_g = kt * 64 + cb * 16 + lr;
          if (kv_g > q_g) sacc[cb][rg] = -INFINITY;
        }
    }

    float pmax[4];
#pragma unroll
    for (int rg = 0; rg < 4; ++rg)
      pmax[rg] = fmaxf(fmaxf(sacc[0][rg], sacc[1][rg]), fmaxf(sacc[2][rg], sacc[3][rg]));
#pragma unroll
    for (int off = 1; off < 16; off <<= 1)
#pragma unroll
      for (int rg = 0; rg < 4; ++rg)
        pmax[rg] = fmaxf(pmax[rg], __shfl_xor(pmax[rg], off, 64));

    // defer-max: skip O-rescale when per-tile max growth <= 8 (log2 domain).
    int nochange = (pmax[0] <= m_r[0] + 8.f) & (pmax[1] <= m_r[1] + 8.f) &
                   (pmax[2] <= m_r[2] + 8.f) & (pmax[3] <= m_r[3] + 8.f);
    if (!__all(nochange)) {
      float alpha[4];
#pragma unroll
      for (int rg = 0; rg < 4; ++rg) {
        float mn = fmaxf(m_r[rg], pmax[rg]);
        alpha[rg] = exp2f(m_r[rg] - mn);
        m_r[rg] = mn;
        l_r[rg] *= alpha[rg];
      }
#pragma unroll
      for (int vb = 0; vb < 8; ++vb)
#pragma unroll
        for (int rg = 0; rg < 4; ++rg)
          acc_o[vb][rg] *= alpha[rg];
    }

    float psum[4] = { 0.f, 0.f, 0.f, 0.f };
#pragma unroll
    for (int cb = 0; cb < 4; ++cb)
#pragma unroll
      for (int rg = 0; rg < 4; ++rg) {
        float pv = exp2f(sacc[cb][rg] - m_r[rg]);
        sacc[cb][rg] = pv;
        psum[rg] += pv;
      }
#pragma unroll
    for (int off = 1; off < 16; off <<= 1)
#pragma unroll
      for (int rg = 0; rg < 4; ++rg)
        psum[rg] += __shfl_xor(psum[rg], off, 64);
#pragma unroll
    for (int rg = 0; rg < 4; ++rg) l_r[rg] += psum[rg];

    // P -> per-wave LDS (same-wave RAW only)
    u16* psw = &Ps[wid * (16 * 88)];
#pragma unroll
    for (int cb = 0; cb < 4; ++cb)
#pragma unroll
      for (int rg = 0; rg < 4; ++rg)
        psw[(lg * 4 + rg) * 88 + cb * 16 + lr] = f2b(sacc[cb][rg]);

    bf16x8 pa[2];
#pragma unroll
    for (int ks = 0; ks < 2; ++ks) pa[ks] = ld_bf8(&psw[lr * 88 + ks * 32 + lg * 8]);
#pragma unroll
    for (int vb = 0; vb < 8; ++vb) {
#pragma unroll
      for (int ks = 0; ks < 2; ++ks) {
        bf16x8 vv = ld_bf8(&Vs[(vb * 16 + lr) * 72 + ks * 32 + lg * 8]);
        acc_o[vb] = __builtin_amdgcn_mfma_f32_16x16x32_bf16(pa[ks], vv, acc_o[vb], 0, 0, 0);
      }
    }
  }

  // epilogue: O[b][s][h*128+d] bf16
#pragma unroll
  for (int vb = 0; vb < 8; ++vb)
#pragma unroll
    for (int rg = 0; rg < 4; ++rg) {
      int s_glob = q0 + wid * 16 + lg * 4 + rg;
      int col = vb * 16 + lr;
      O[((size_t)b * S_LEN + s_glob) * EMB + h * HD + col] = f2b(acc_o[vb][rg] / l_r[rg]);
    }
}

extern "C" void kernel_launch(void* const* d_in, const int* in_sizes, int n_in,
                              void* d_out, int out_size, void* d_ws, size_t ws_size,
                              hipStream_t stream) {
  const float* xf    = (const float*)d_in[0];
  const float* wckvf = (const float*)d_in[1];
  const float* wkf   = (const float*)d_in[2];
  const float* wvf   = (const float*)d_in[3];
  const float* wcqf  = (const float*)d_in[4];
  const float* wqf   = (const float*)d_in[5];
  const float* wqrf  = (const float*)d_in[6];
  const float* wkrf  = (const float*)d_in[7];
  const float* wof   = (const float*)d_in[8];
  (void)in_sizes; (void)n_in; (void)out_size; (void)ws_size;

  u16* ws = (u16*)d_ws;
  size_t off = 0;
  auto alloc = [&](size_t n) -> u16* { u16* p = ws + off; off += n; return p; };
  u16* XB     = alloc(8388608);   // x bf16 [4096,2048]
  // W1_T group [1088,2048]: wckv rows 0..511, wcq 512..1023, wkr 1024..1087
  u16* WCKV_T = alloc(1048576);
  u16* WCQ_T  = alloc(1048576);
  u16* WKR_T  = alloc(131072);
  // Fused weight block [7168,512]: wk | wv | wq | wqr
  u16* WK_T   = alloc(1048576);
  u16* WV_T   = alloc(1048576);
  u16* WQ_T   = alloc(1048576);
  u16* WQR_T  = alloc(524288);
  u16* WO_T   = alloc(4194304);   // [2048,2048]
  u16* CC     = alloc(4456448);   // [4096,1088]: ckv | cq | kr
  u16* QR     = alloc(4194304);   // [4096,1024]
  u16* QCAT   = alloc(12582912);  // [B,H,S,192]
  u16* KCAT   = alloc(12582912);
  u16* VT     = alloc(8388608);   // [B,H,128,S]
  u16* AOUT   = alloc(8388608);   // [4096,2048]
  float* COS_T = (float*)alloc(131072);
  float* SIN_T = (float*)alloc(131072);

  // Fused prep: f2b(x) + all weight transposes + rope table.
  prep_kernel<<<10912, 256, 0, stream>>>(xf, XB,
                                         wckvf, WCKV_T, wcqf, WCQ_T, wkrf, WKR_T,
                                         wkf, WK_T, wvf, WV_T, wqf, WQ_T,
                                         wqrf, WQR_T, wof, WO_T,
                                         COS_T, SIN_T);

  const float SC = 0.07216878364870323f * 1.4426950408889634f;  // 1/sqrt(192)*log2e
  // G1: x @ [w_ckv | w_cq | w_kr]  -> CC [4096,1088].  288 blocks.
  gemm_bt_kernel<0><<<288, 256, 0, stream>>>(XB, 2048, WCKV_T, CC,
                                             nullptr, nullptr, nullptr,
                                             4096, 1088, 2048, 9, 1.0f);
  // G23: {c_kv,c_q} @ [wk|wv|wq|wqr] -> KCAT + VT + QCAT(scaled) + QR.
  gemm_bt_kernel<6><<<1792, 256, 0, stream>>>(CC, 1088, WK_T, KCAT, VT, QCAT, QR,
                                              4096, 7168, 512, 56, SC);

  rope_assemble_kernel<<<8192, 256, 0, stream>>>(QR, CC, COS_T, SIN_T, QCAT, KCAT);

  attn_kernel<<<512, 512, 0, stream>>>(QCAT, KCAT, VT, AOUT);

  // G4: attn_out @ w_o -> d_out (fp32). 512 blocks.
  gemm_bt_kernel<1><<<512, 256, 0, stream>>>(AOUT, 2048, WO_T, d_out,
                                             nullptr, nullptr, nullptr,
                                             4096, 2048, 2048, 16, 1.0f);
}

// Round 19
// 269.313 us; speedup vs baseline: 2.3213x; 1.0265x over previous
//
#include <hip/hip_runtime.h>

// MLA v3 forward, MI355X/gfx950. Round 19.
// Single change vs round 18: attn softmax exp2f -> __builtin_amdgcn_exp2f
// (raw v_exp_f32). Plain exp2f without -ffast-math is a guarded OCML call
// (r16/r18: VALUBusy 28.5->34, attn +5.5us); the builtin is one instruction
// and keeps the log2-domain scale fold.

typedef unsigned short u16;
typedef __attribute__((ext_vector_type(8))) short s16x8;
typedef __attribute__((ext_vector_type(4))) float f32x4;
typedef __attribute__((ext_vector_type(8))) __bf16 bf16x8;
typedef __attribute__((ext_vector_type(4))) u16 u16x4;

#define S_LEN 2048
#define NH 16
#define HD 128
#define DQK 192
#define EMB 2048

#define GLOAD_LDS16(g, l)                                                      \
  __builtin_amdgcn_global_load_lds(                                            \
      (const __attribute__((address_space(1))) unsigned int*)(g),              \
      (__attribute__((address_space(3))) unsigned int*)(l), 16, 0, 0)

__device__ __forceinline__ u16 f2b(float f) {
  unsigned u = __builtin_bit_cast(unsigned, f);
  u += 0x7FFFu + ((u >> 16) & 1u);           // RNE to bf16
  return (u16)(u >> 16);
}
__device__ __forceinline__ float b2f(u16 v) {
  unsigned u = ((unsigned)v) << 16;
  return __builtin_bit_cast(float, u);
}
__device__ __forceinline__ bf16x8 ld_bf8(const u16* p) {
  return __builtin_bit_cast(bf16x8, *(const s16x8*)p);
}

// Transpose one 64x64 tile: in f32 [K][N] -> out bf16 [N][K].
__device__ __forceinline__ void transpose_tile(const float* __restrict__ in,
                                               u16* __restrict__ out,
                                               int K, int N, int local, int t,
                                               u16* T /* [64*72] LDS */) {
  int nt = N >> 6;
  int n0 = (local % nt) * 64, k0 = (local / nt) * 64;
#pragma unroll
  for (int r = 0; r < 4; ++r) {
    int kl = (t >> 4) + r * 16, nl = (t & 15) * 4;
    f32x4 v = *(const f32x4*)(in + (size_t)(k0 + kl) * N + n0 + nl);
#pragma unroll
    for (int j = 0; j < 4; ++j) T[(nl + j) * 72 + kl] = f2b(v[j]);
  }
  __syncthreads();
#pragma unroll
  for (int r = 0; r < 2; ++r) {
    int chunk = t + r * 256, nr = chunk >> 3, kc = (chunk & 7) * 8;
    *(s16x8*)(out + (size_t)(n0 + nr) * K + k0 + kc) = *(const s16x8*)(&T[nr * 72 + kc]);
  }
}

// Fused prep: [0,8192) f2b(x); then 8 weight transposes; then rope table.
__global__ __launch_bounds__(256) void prep_kernel(
    const float* __restrict__ xf, u16* __restrict__ XB,
    const float* __restrict__ wckvf, u16* __restrict__ WCKV_T,
    const float* __restrict__ wcqf,  u16* __restrict__ WCQ_T,
    const float* __restrict__ wkrf,  u16* __restrict__ WKR_T,
    const float* __restrict__ wkf,   u16* __restrict__ WK_T,
    const float* __restrict__ wvf,   u16* __restrict__ WV_T,
    const float* __restrict__ wqf,   u16* __restrict__ WQ_T,
    const float* __restrict__ wqrf,  u16* __restrict__ WQR_T,
    const float* __restrict__ wof,   u16* __restrict__ WO_T,
    float* __restrict__ cosT, float* __restrict__ sinT) {
  __shared__ u16 T[64 * 72];
  const int id = blockIdx.x, t = threadIdx.x;
  if (id < 8192) {                       // x f32 -> bf16, 4 el/thread
    int i = id * 256 + t;                // n4 = 2097152 exactly
    f32x4 v = *(const f32x4*)(xf + (size_t)i * 4);
    u16x4 o = { f2b(v[0]), f2b(v[1]), f2b(v[2]), f2b(v[3]) };
    *(u16x4*)(XB + (size_t)i * 4) = o;
  } else if (id < 8448)  { transpose_tile(wckvf, WCKV_T, 2048, 512,  id - 8192, t, T); }
  else if (id < 8704)    { transpose_tile(wcqf,  WCQ_T,  2048, 512,  id - 8448, t, T); }
  else if (id < 8736)    { transpose_tile(wkrf,  WKR_T,  2048, 64,   id - 8704, t, T); }
  else if (id < 8992)    { transpose_tile(wkf,   WK_T,   512,  2048, id - 8736, t, T); }
  else if (id < 9248)    { transpose_tile(wvf,   WV_T,   512,  2048, id - 8992, t, T); }
  else if (id < 9504)    { transpose_tile(wqf,   WQ_T,   512,  2048, id - 9248, t, T); }
  else if (id < 9632)    { transpose_tile(wqrf,  WQR_T,  512,  1024, id - 9504, t, T); }
  else if (id < 10656)   { transpose_tile(wof,   WO_T,   2048, 2048, id - 9632, t, T); }
  else {                                 // rope cos/sin table, 65536 entries
    int i2 = (id - 10656) * 256 + t;
    int s = i2 >> 5, i = i2 & 31;
    float inv = exp2f(-(float)i * (13.287712379549449f / 32.0f));
    float ang = (float)s * inv;
    cosT[i2] = cosf(ang);
    sinT[i2] = sinf(ang);
  }
}

// C = A[M,K](lda) @ BT[N,K]^T, bf16 in, fp32 accum. 128x128 tile, BK=64.
// 1D grid + XCD-chunked swizzle (gridDim.x % 8 == 0 required).
// MODE 0: bf16 [M,N]->C0; MODE 1: fp32 [M,N]->C0;
// MODE 6 (fused G2+G3, N=7168, bn0>=4096 uses A+512):
//   col<2048 -> KCAT(C0)[b,h,s,192]; col<4096 -> VT(C1)[b,h,d,s];
//   col<6144 -> QCAT(C2)*scale; else -> QR(C3)[M,1024].
template<int MODE>
__global__ __launch_bounds__(256) void gemm_bt_kernel(const u16* __restrict__ A,
                                                      int lda,
                                                      const u16* __restrict__ BT,
                                                      void* __restrict__ C0,
                                                      void* __restrict__ C1,
                                                      void* __restrict__ C2,
                                                      void* __restrict__ C3,
                                                      int M, int N, int K,
                                                      int nx, float scale) {
  __shared__ __align__(16) u16 As[2][128 * 64];
  __shared__ __align__(16) u16 Bs[2][128 * 64];
  const int t = threadIdx.x;
  const int lane = t & 63, wid = t >> 6;
  const int wr = (wid >> 1) * 64, wc = (wid & 1) * 64;
  const int cpx = gridDim.x >> 3;
  int wg = blockIdx.x;
  wg = (wg & 7) * cpx + (wg >> 3);
  const int bn0 = (wg % nx) * 128;
  const int bm0 = (wg / nx) * 128;
  if (MODE == 6 && bn0 >= 4096) A += 512;   // G3 part reads c_q slice
  const int lr = lane & 15, lg = lane >> 4;

  auto stage = [&](int k0, int buf) {
#pragma unroll
    for (int r = 0; r < 4; ++r) {
      int chunk = t + r * 256;
      int row = chunk >> 3, kcs = (chunk & 7) * 8;
      int kcg = kcs ^ ((row & 7) << 3);      // inverse swizzle on SOURCE
      GLOAD_LDS16(A + (size_t)(bm0 + row) * lda + k0 + kcg, &As[buf][chunk * 8]);
      GLOAD_LDS16(BT + (size_t)(bn0 + row) * K + k0 + kcg, &Bs[buf][chunk * 8]);
    }
  };

  f32x4 acc[4][4] = {};
  const int nt = K >> 6;
  stage(0, 0);
  for (int tk = 0; tk < nt; ++tk) {
    const int cur = tk & 1;
    __syncthreads();
    if (tk + 1 < nt) stage((tk + 1) << 6, cur ^ 1);
#pragma unroll
    for (int kk = 0; kk < 2; ++kk) {
      bf16x8 af[4], bfr[4];
      const int kbase = kk * 32 + lg * 8;
#pragma unroll
      for (int m = 0; m < 4; ++m) {
        int row = wr + m * 16 + lr;
        af[m] = ld_bf8(&As[cur][row * 64 + (kbase ^ ((row & 7) << 3))]);
      }
#pragma unroll
      for (int n = 0; n < 4; ++n) {
        int row = wc + n * 16 + lr;
        bfr[n] = ld_bf8(&Bs[cur][row * 64 + (kbase ^ ((row & 7) << 3))]);
      }
#pragma unroll
      for (int m = 0; m < 4; ++m)
#pragma unroll
        for (int n = 0; n < 4; ++n)
          acc[m][n] = __builtin_amdgcn_mfma_f32_16x16x32_bf16(af[m], bfr[n], acc[m][n], 0, 0, 0);
    }
  }

  // C/D layout: col = lane&15, row = (lane>>4)*4 + reg
#pragma unroll
  for (int m = 0; m < 4; ++m)
#pragma unroll
    for (int n = 0; n < 4; ++n)
#pragma unroll
      for (int rg = 0; rg < 4; ++rg) {
        int row = bm0 + wr + m * 16 + lg * 4 + rg;
        int col = bn0 + wc + n * 16 + lr;
        if (col >= N) continue;
        float v = acc[m][n][rg];
        if (MODE == 0) {
          ((u16*)C0)[(size_t)row * N + col] = f2b(v * scale);
        } else if (MODE == 1) {
          ((float*)C0)[(size_t)row * N + col] = v * scale;
        } else {  // MODE 6
          int bb = row >> 11, s = row & 2047;
          if (col < 2048) {
            int h = col >> 7, d = col & 127;
            ((u16*)C0)[((size_t)(bb * NH + h) * S_LEN + s) * DQK + d] = f2b(v);
          } else if (col < 4096) {
            int c2 = col - 2048, h = c2 >> 7, d = c2 & 127;
            ((u16*)C1)[((size_t)(bb * NH + h) * HD + d) * S_LEN + s] = f2b(v);
          } else if (col < 6144) {
            int c3 = col - 4096, h = c3 >> 7, d = c3 & 127;
            ((u16*)C2)[((size_t)(bb * NH + h) * S_LEN + s) * DQK + d] = f2b(v * scale);
          } else {
            ((u16*)C3)[(size_t)row * 1024 + (col - 6144)] = f2b(v);
          }
        }
      }
}

// Fill rope halves of Qcat/Kcat. kr lives in CC cols 1024..1087 (stride 1088).
// Q rope half scaled by SC*log2(e) (exp2 softmax domain).
__global__ __launch_bounds__(256) void rope_assemble_kernel(const u16* __restrict__ qr,
                                                            const u16* __restrict__ cc,
                                                            const float* __restrict__ cosT,
                                                            const float* __restrict__ sinT,
                                                            u16* __restrict__ Qcat,
                                                            u16* __restrict__ Kcat) {
  int id = blockIdx.x * 256 + threadIdx.x;   // B*H*S*32 = 2^21
  int i = id & 31;
  int s = (id >> 5) & 2047;
  int h = (id >> 16) & 15;
  int b = id >> 20;
  float c = cosT[(s << 5) + i], sn = sinT[(s << 5) + i];
  const float SC = 0.07216878364870323f * 1.4426950408889634f;  // 1/sqrt(192)*log2e

  size_t qbase = ((size_t)b * S_LEN + s) * 1024 + h * 64 + 2 * i;
  float qe = b2f(qr[qbase]), qo = b2f(qr[qbase + 1]);
  size_t obase = ((size_t)(b * NH + h) * S_LEN + s) * DQK + HD + 2 * i;
  Qcat[obase]     = f2b((qe * c - qo * sn) * SC);
  Qcat[obase + 1] = f2b((qe * sn + qo * c) * SC);

  size_t kbase = ((size_t)b * S_LEN + s) * 1088 + 1024 + 2 * i;
  float ke = b2f(cc[kbase]), ko = b2f(cc[kbase + 1]);
  Kcat[obase]     = f2b(ke * c - ko * sn);
  Kcat[obase + 1] = f2b(ke * sn + ko * c);
}

// Flash attention, causal. Round-15 structure + raw-v_exp softmax (log2
// domain) + defer-max. 8 waves, QBLK=128, kv tile 64. Grid 512; balanced.
__global__ __launch_bounds__(512, 2) void attn_kernel(const u16* __restrict__ Q,
                                                      const u16* __restrict__ K,
                                                      const u16* __restrict__ VT,
                                                      u16* __restrict__ O) {
  __shared__ u16 Ks[64 * 200];    // [kv][d0..191]
  __shared__ u16 Vs[128 * 72];    // [d][kv0..63]
  __shared__ u16 Ps[8 * 16 * 88]; // per-wave [q][kv]
  const int id = blockIdx.x;
  const int p8 = id >> 5, hb = id & 31;
  const int h = hb & 15, b = hb >> 4;
  const int qb = (p8 < 8) ? p8 : 23 - p8;
  const int q0 = qb * 128;
  const int t = threadIdx.x, lane = t & 63, wid = t >> 6;
  const int lr = lane & 15, lg = lane >> 4;
  const size_t qk_head = (size_t)(b * NH + h) * S_LEN * DQK;
  const size_t vt_head = (size_t)(b * NH + h) * HD * S_LEN;

  s16x8 kst[3], vst[2];
  auto gload = [&](int kt) {
#pragma unroll
    for (int r = 0; r < 3; ++r) {
      int chunk = t + r * 512, row = chunk / 24, cc = chunk % 24;
      kst[r] = *(const s16x8*)(K + qk_head + (size_t)(kt * 64 + row) * DQK + cc * 8);
    }
#pragma unroll
    for (int r = 0; r < 2; ++r) {
      int chunk = t + r * 512, d = chunk >> 3, cc = chunk & 7;
      vst[r] = *(const s16x8*)(VT + vt_head + (size_t)d * S_LEN + kt * 64 + cc * 8);
    }
  };
  auto swr = [&]() {
#pragma unroll
    for (int r = 0; r < 3; ++r) {
      int chunk = t + r * 512, row = chunk / 24, cc = chunk % 24;
      *(s16x8*)(&Ks[row * 200 + cc * 8]) = kst[r];
    }
#pragma unroll
    for (int r = 0; r < 2; ++r) {
      int chunk = t + r * 512, d = chunk >> 3, cc = chunk & 7;
      *(s16x8*)(&Vs[d * 72 + cc * 8]) = vst[r];
    }
  };

  bf16x8 qa[6];
  {
    const u16* qrow = Q + qk_head + (size_t)(q0 + wid * 16 + lr) * DQK;
#pragma unroll
    for (int ks = 0; ks < 6; ++ks) qa[ks] = ld_bf8(qrow + ks * 32 + lg * 8);
  }

  f32x4 acc_o[8] = {};
  float m_r[4] = { -INFINITY, -INFINITY, -INFINITY, -INFINITY };
  float l_r[4] = { 0.f, 0.f, 0.f, 0.f };

  const int nt = 2 * qb + 2;
  gload(0);
#pragma unroll 1
  for (int kt = 0; kt < nt; ++kt) {
    __syncthreads();                 // all waves done reading previous tile
    swr();                           // stage tile kt
    if (kt + 1 < nt) gload(kt + 1);  // prefetch next
    __syncthreads();                 // tile kt visible

    f32x4 sacc[4];
#pragma unroll
    for (int cb = 0; cb < 4; ++cb) {
      f32x4 sv = {};
#pragma unroll
      for (int ks = 0; ks < 6; ++ks) {
        bf16x8 kb = ld_bf8(&Ks[(cb * 16 + lr) * 200 + ks * 32 + lg * 8]);
        sv = __builtin_amdgcn_mfma_f32_16x16x32_bf16(qa[ks], kb, sv, 0, 0, 0);
      }
      sacc[cb] = sv;
    }

    if (kt >= 2 * qb) {              // diagonal tiles: causal mask
#pragma unroll
      for (int cb = 0; cb < 4; ++cb)
#pragma unroll
        for (int rg = 0; rg < 4; ++rg) {
          int q_g = q0 + wid * 16 + lg * 4 + rg;
          int kv_g = kt * 64 + cb * 16 + lr;
          if (kv_g > q_g) sacc[cb][rg] = -INFINITY;
        }
    }

    float pmax[4];
#pragma unroll
    for (int rg = 0; rg < 4; ++rg)
      pmax[rg] = fmaxf(fmaxf(sacc[0][rg], sacc[1][rg]), fmaxf(sacc[2][rg], sacc[3][rg]));
#pragma unroll
    for (int off = 1; off < 16; off <<= 1)
#pragma unroll
      for (int rg = 0; rg < 4; ++rg)
        pmax[rg] = fmaxf(pmax[rg], __shfl_xor(pmax[rg], off, 64));

    // defer-max: skip O-rescale when per-tile max growth <= 8 (log2 domain).
    int nochange = (pmax[0] <= m_r[0] + 8.f) & (pmax[1] <= m_r[1] + 8.f) &
                   (pmax[2] <= m_r[2] + 8.f) & (pmax[3] <= m_r[3] + 8.f);
    if (!__all(nochange)) {
      float alpha[4];
#pragma unroll
      for (int rg = 0; rg < 4; ++rg) {
        float mn = fmaxf(m_r[rg], pmax[rg]);
        alpha[rg] = __builtin_amdgcn_exp2f(m_r[rg] - mn);
        m_r[rg] = mn;
        l_r[rg] *= alpha[rg];
      }
#pragma unroll
      for (int vb = 0; vb < 8; ++vb)
#pragma unroll
        for (int rg = 0; rg < 4; ++rg)
          acc_o[vb][rg] *= alpha[rg];
    }

    float psum[4] = { 0.f, 0.f, 0.f, 0.f };
#pragma unroll
    for (int cb = 0; cb < 4; ++cb)
#pragma unroll
      for (int rg = 0; rg < 4; ++rg) {
        float pv = __builtin_amdgcn_exp2f(sacc[cb][rg] - m_r[rg]);
        sacc[cb][rg] = pv;
        psum[rg] += pv;
      }
#pragma unroll
    for (int off = 1; off < 16; off <<= 1)
#pragma unroll
      for (int rg = 0; rg < 4; ++rg)
        psum[rg] += __shfl_xor(psum[rg], off, 64);
#pragma unroll
    for (int rg = 0; rg < 4; ++rg) l_r[rg] += psum[rg];

    // P -> per-wave LDS (same-wave RAW only)
    u16* psw = &Ps[wid * (16 * 88)];
#pragma unroll
    for (int cb = 0; cb < 4; ++cb)
#pragma unroll
      for (int rg = 0; rg < 4; ++rg)
        psw[(lg * 4 + rg) * 88 + cb * 16 + lr] = f2b(sacc[cb][rg]);

    bf16x8 pa[2];
#pragma unroll
    for (int ks = 0; ks < 2; ++ks) pa[ks] = ld_bf8(&psw[lr * 88 + ks * 32 + lg * 8]);
#pragma unroll
    for (int vb = 0; vb < 8; ++vb) {
#pragma unroll
      for (int ks = 0; ks < 2; ++ks) {
        bf16x8 vv = ld_bf8(&Vs[(vb * 16 + lr) * 72 + ks * 32 + lg * 8]);
        acc_o[vb] = __builtin_amdgcn_mfma_f32_16x16x32_bf16(pa[ks], vv, acc_o[vb], 0, 0, 0);
      }
    }
  }

  // epilogue: O[b][s][h*128+d] bf16
#pragma unroll
  for (int vb = 0; vb < 8; ++vb)
#pragma unroll
    for (int rg = 0; rg < 4; ++rg) {
      int s_glob = q0 + wid * 16 + lg * 4 + rg;
      int col = vb * 16 + lr;
      O[((size_t)b * S_LEN + s_glob) * EMB + h * HD + col] = f2b(acc_o[vb][rg] / l_r[rg]);
    }
}

extern "C" void kernel_launch(void* const* d_in, const int* in_sizes, int n_in,
                              void* d_out, int out_size, void* d_ws, size_t ws_size,
                              hipStream_t stream) {
  const float* xf    = (const float*)d_in[0];
  const float* wckvf = (const float*)d_in[1];
  const float* wkf   = (const float*)d_in[2];
  const float* wvf   = (const float*)d_in[3];
  const float* wcqf  = (const float*)d_in[4];
  const float* wqf   = (const float*)d_in[5];
  const float* wqrf  = (const float*)d_in[6];
  const float* wkrf  = (const float*)d_in[7];
  const float* wof   = (const float*)d_in[8];
  (void)in_sizes; (void)n_in; (void)out_size; (void)ws_size;

  u16* ws = (u16*)d_ws;
  size_t off = 0;
  auto alloc = [&](size_t n) -> u16* { u16* p = ws + off; off += n; return p; };
  u16* XB     = alloc(8388608);   // x bf16 [4096,2048]
  // W1_T group [1088,2048]: wckv rows 0..511, wcq 512..1023, wkr 1024..1087
  u16* WCKV_T = alloc(1048576);
  u16* WCQ_T  = alloc(1048576);
  u16* WKR_T  = alloc(131072);
  // Fused weight block [7168,512]: wk | wv | wq | wqr
  u16* WK_T   = alloc(1048576);
  u16* WV_T   = alloc(1048576);
  u16* WQ_T   = alloc(1048576);
  u16* WQR_T  = alloc(524288);
  u16* WO_T   = alloc(4194304);   // [2048,2048]
  u16* CC     = alloc(4456448);   // [4096,1088]: ckv | cq | kr
  u16* QR     = alloc(4194304);   // [4096,1024]
  u16* QCAT   = alloc(12582912);  // [B,H,S,192]
  u16* KCAT   = alloc(12582912);
  u16* VT     = alloc(8388608);   // [B,H,128,S]
  u16* AOUT   = alloc(8388608);   // [4096,2048]
  float* COS_T = (float*)alloc(131072);
  float* SIN_T = (float*)alloc(131072);

  // Fused prep: f2b(x) + all weight transposes + rope table.
  prep_kernel<<<10912, 256, 0, stream>>>(xf, XB,
                                         wckvf, WCKV_T, wcqf, WCQ_T, wkrf, WKR_T,
                                         wkf, WK_T, wvf, WV_T, wqf, WQ_T,
                                         wqrf, WQR_T, wof, WO_T,
                                         COS_T, SIN_T);

  const float SC = 0.07216878364870323f * 1.4426950408889634f;  // 1/sqrt(192)*log2e
  // G1: x @ [w_ckv | w_cq | w_kr]  -> CC [4096,1088].  288 blocks.
  gemm_bt_kernel<0><<<288, 256, 0, stream>>>(XB, 2048, WCKV_T, CC,
                                             nullptr, nullptr, nullptr,
                                             4096, 1088, 2048, 9, 1.0f);
  // G23: {c_kv,c_q} @ [wk|wv|wq|wqr] -> KCAT + VT + QCAT(scaled) + QR.
  gemm_bt_kernel<6><<<1792, 256, 0, stream>>>(CC, 1088, WK_T, KCAT, VT, QCAT, QR,
                                              4096, 7168, 512, 56, SC);

  rope_assemble_kernel<<<8192, 256, 0, stream>>>(QR, CC, COS_T, SIN_T, QCAT, KCAT);

  attn_kernel<<<512, 512, 0, stream>>>(QCAT, KCAT, VT, AOUT);

  // G4: attn_out @ w_o -> d_out (fp32). 512 blocks.
  gemm_bt_kernel<1><<<512, 256, 0, stream>>>(AOUT, 2048, WO_T, d_out,
                                             nullptr, nullptr, nullptr,
                                             4096, 2048, 2048, 16, 1.0f);
}